// Round 3
// baseline (336.240 us; speedup 1.0000x reference)
//
#include <hip/hip_runtime.h>
#include <math.h>

#define BB 2
#define NN 512
#define DD 128
#define HH 8
#define DKK 16
#define MC 256   // m-chunk rows per eg_kernel block

// ---------------- Kernel 1: QKV projection ----------------
__global__ __launch_bounds__(128)
void qkv_kernel(const float* __restrict__ n_in,
                const float* __restrict__ W_qkv,
                float* __restrict__ Qw, float* __restrict__ Kw, float* __restrict__ Vw)
{
    __shared__ float nrow[DD];
    const int bn = blockIdx.x;
    const int b  = bn >> 9;
    const int nr = bn & 511;
    const int t  = threadIdx.x;
    nrow[t] = n_in[(size_t)bn * DD + t];
    __syncthreads();
    const int h = t >> 4, dk = t & 15;
    const size_t dst = ((size_t)(b * HH + h) * NN + nr) * DKK + dk;
    float accq = 0.f, acck = 0.f, accv = 0.f;
    #pragma unroll 8
    for (int d = 0; d < DD; ++d) {
        const float nv = nrow[d];
        const float* wr = W_qkv + (size_t)d * 3 * DD;
        accq += nv * wr[t];
        acck += nv * wr[t + 128];
        accv += nv * wr[t + 256];
    }
    Qw[dst] = accq;
    Kw[dst] = acck;
    Vw[dst] = accv;
}

// ---------------- Kernel 2: E/G + QK + e_out, per (b,n, m-chunk) ----------------
// grid = B*N*2 blocks, 256 threads (4 waves). Block handles MC=256 m-rows.
__global__ __launch_bounds__(256)
void eg_kernel(const float* __restrict__ e,
               const float* __restrict__ W_g,
               const float* __restrict__ W_e,
               const float* __restrict__ O_e,
               const float* __restrict__ Qw,
               const float* __restrict__ Kw,
               float* __restrict__ EGw,      // [B*N][H][NN]  (_E, for attn kernel)
               float* __restrict__ Gpart,    // [B*N*2][H]    (partial sigmoid sums)
               float* __restrict__ e_out)
{
    __shared__ __align__(16) float W_egT[16 * DD];   // [hh][d]
    __shared__ __align__(16) float ET[HH * MC];      // [h][m_local]
    __shared__ __align__(16) float Oe_lds[HH * DD];  // [h][d]
    __shared__ __align__(16) float q_lds[DD];        // h-major Q row

    const int t    = threadIdx.x;
    const int bid  = blockIdx.x;
    const int bn   = bid >> 1;
    const int mc   = bid & 1;
    const int b    = bn >> 9;
    const int nr   = bn & 511;
    const int wq   = t >> 6;
    const int lane = t & 63;

    for (int i = t; i < 16 * DD; i += 256) {
        const int hh = i >> 7, d = i & 127;
        W_egT[i] = (hh < 8) ? W_e[d * HH + hh] : W_g[d * HH + (hh - 8)];
    }
    for (int i = t; i < HH * DD; i += 256) Oe_lds[i] = O_e[i];
    if (t < DD)
        q_lds[t] = Qw[((size_t)(b * HH + (t >> 4)) * NN + nr) * DKK + (t & 15)];
    __syncthreads();

    // ---- Phase A: E (waves 0,1) and G partial sums (waves 2,3) over 256 rows ----
    float acc[4][4];
    #pragma unroll
    for (int j = 0; j < 4; ++j)
        #pragma unroll
        for (int rr = 0; rr < 4; ++rr) acc[j][rr] = 0.f;

    const float4* __restrict__ e4 =
        (const float4*)(e + ((size_t)bn * NN + (size_t)mc * MC) * DD);
    for (int d16 = 0; d16 < 8; ++d16) {
        float4 w4[4][4];
        #pragma unroll
        for (int j = 0; j < 4; ++j)
            #pragma unroll
            for (int k = 0; k < 4; ++k)
                w4[j][k] = *(const float4*)&W_egT[(4 * wq + j) * DD + d16 * 16 + k * 4];
        #pragma unroll
        for (int rr = 0; rr < 4; ++rr) {
            const float4* ep = e4 + (size_t)(rr * 64 + lane) * 32 + d16 * 4; // 64B/lane
            #pragma unroll
            for (int k = 0; k < 4; ++k) {
                const float4 ev = ep[k];
                #pragma unroll
                for (int j = 0; j < 4; ++j)
                    acc[j][rr] += ev.x * w4[j][k].x + ev.y * w4[j][k].y
                                + ev.z * w4[j][k].z + ev.w * w4[j][k].w;
            }
        }
    }

    if (wq < 2) {
        #pragma unroll
        for (int j = 0; j < 4; ++j) {
            const int h = 4 * wq + j;
            #pragma unroll
            for (int rr = 0; rr < 4; ++rr)
                ET[h * MC + rr * 64 + lane] = acc[j][rr];
        }
    } else {
        #pragma unroll
        for (int j = 0; j < 4; ++j) {
            float gs = 0.f;
            #pragma unroll
            for (int rr = 0; rr < 4; ++rr)
                gs += 1.f / (1.f + __expf(-acc[j][rr]));
            #pragma unroll
            for (int off = 32; off >= 1; off >>= 1)
                gs += __shfl_xor(gs, off, 64);
            if (lane == 0) Gpart[(size_t)bid * HH + (wq - 2) * 4 + j] = gs;
        }
    }
    __syncthreads();

    // ---- Phase QK: _E = clamp(QK^T * scale) + E ; each wave 2 heads ----
    #pragma unroll
    for (int hw = 0; hw < 2; ++hw) {
        const int h = wq * 2 + hw;
        const float4* __restrict__ kb =
            (const float4*)(Kw + ((size_t)(b * HH + h) * NN + (size_t)mc * MC) * DKK);
        const float4 q0 = *(const float4*)&q_lds[h * 16 + 0];
        const float4 q1 = *(const float4*)&q_lds[h * 16 + 4];
        const float4 q2 = *(const float4*)&q_lds[h * 16 + 8];
        const float4 q3 = *(const float4*)&q_lds[h * 16 + 12];
        #pragma unroll
        for (int k = 0; k < 4; ++k) {
            const int m = k * 64 + lane;
            const float4 k0 = kb[m * 4 + 0];
            const float4 k1 = kb[m * 4 + 1];
            const float4 k2 = kb[m * 4 + 2];
            const float4 k3 = kb[m * 4 + 3];
            float s = q0.x*k0.x + q0.y*k0.y + q0.z*k0.z + q0.w*k0.w
                    + q1.x*k1.x + q1.y*k1.y + q1.z*k1.z + q1.w*k1.w
                    + q2.x*k2.x + q2.y*k2.y + q2.z*k2.z + q2.w*k2.w
                    + q3.x*k3.x + q3.y*k3.y + q3.z*k3.z + q3.w*k3.w;
            s *= 0.25f;
            s = fminf(5.f, fmaxf(-5.f, s));
            const float val = s + ET[h * MC + m];
            ET[h * MC + m] = val;
            EGw[((size_t)bn * HH + h) * NN + (size_t)mc * MC + m] = val;
        }
    }
    __syncthreads();

    // ---- Phase D: e_out tile = sum_h _E[h][m] * O_e[h,:] ----
    const int c4 = t & 31;
    const int mb = t >> 5;
    float4 oe[8];
    #pragma unroll
    for (int h = 0; h < 8; ++h)
        oe[h] = *(const float4*)&Oe_lds[h * DD + c4 * 4];
    float4* __restrict__ out4 =
        (float4*)(e_out + ((size_t)bn * NN + (size_t)mc * MC) * DD);
    for (int k = 0; k < 32; ++k) {
        const int m = mb + k * 8;
        float4 r{0.f, 0.f, 0.f, 0.f};
        #pragma unroll
        for (int h = 0; h < 8; ++h) {
            const float ev = ET[h * MC + m];
            r.x += ev * oe[h].x;
            r.y += ev * oe[h].y;
            r.z += ev * oe[h].z;
            r.w += ev * oe[h].w;
        }
        out4[(size_t)m * 32 + c4] = r;
    }
}

// ---------------- Kernel 3: softmax + AV + n_out, per (b,n) ----------------
__global__ __launch_bounds__(256)
void attn_kernel(const float* __restrict__ EGw,
                 const float* __restrict__ Gpart,
                 const float* __restrict__ Vw,
                 const float* __restrict__ O_n,
                 float* __restrict__ n_out)
{
    __shared__ __align__(16) float ET[HH * NN];   // 16KB [h][m]
    __shared__ __align__(16) float vout[DD];
    __shared__ float dc[HH];

    const int t    = threadIdx.x;
    const int bn   = blockIdx.x;
    const int b    = bn >> 9;
    const int wq   = t >> 6;
    const int lane = t & 63;

    const float4* __restrict__ eg4 = (const float4*)(EGw + (size_t)bn * HH * NN);
    float4* et4 = (float4*)ET;
    #pragma unroll
    for (int i = t; i < HH * NN / 4; i += 256) et4[i] = eg4[i];
    if (t < HH)
        dc[t] = log1pf(Gpart[(size_t)(bn * 2) * HH + t] +
                       Gpart[(size_t)(bn * 2 + 1) * HH + t]);
    __syncthreads();

    #pragma unroll 1
    for (int hw = 0; hw < 2; ++hw) {
        const int h = wq * 2 + hw;
        float vals[8];
        float rmax = -1e30f;
        #pragma unroll
        for (int k = 0; k < 8; ++k) {
            vals[k] = ET[h * NN + k * 64 + lane];
            rmax = fmaxf(rmax, vals[k]);
        }
        #pragma unroll
        for (int off = 32; off >= 1; off >>= 1)
            rmax = fmaxf(rmax, __shfl_xor(rmax, off, 64));
        float sum = 0.f;
        #pragma unroll
        for (int k = 0; k < 8; ++k) sum += __expf(vals[k] - rmax);
        #pragma unroll
        for (int off = 32; off >= 1; off >>= 1)
            sum += __shfl_xor(sum, off, 64);
        const float factor = dc[h] / sum;

        const int ddx = lane & 15, mg = lane >> 4;
        const float* __restrict__ vb = Vw + ((size_t)(b * HH + h) * NN) * DKK;
        float av = 0.f;
        #pragma unroll 4
        for (int m = mg; m < NN; m += 4) {
            const float p = __expf(ET[h * NN + m] - rmax);
            av += p * vb[m * DKK + ddx];
        }
        av += __shfl_xor(av, 16, 64);
        av += __shfl_xor(av, 32, 64);
        if (mg == 0) vout[h * DKK + ddx] = av * factor;
    }
    __syncthreads();

    if (t < DD) {
        float a3 = 0.f;
        #pragma unroll 4
        for (int d = 0; d < DD; ++d) a3 += vout[d] * O_n[d * DD + t];
        n_out[(size_t)bn * DD + t] = a3;
    }
}

extern "C" void kernel_launch(void* const* d_in, const int* in_sizes, int n_in,
                              void* d_out, int out_size, void* d_ws, size_t ws_size,
                              hipStream_t stream)
{
    const float* n_ptr = (const float*)d_in[0];
    const float* e     = (const float*)d_in[1];
    const float* W_qkv = (const float*)d_in[2];
    const float* O_n   = (const float*)d_in[3];
    const float* W_g   = (const float*)d_in[4];
    const float* W_e   = (const float*)d_in[5];
    const float* O_e   = (const float*)d_in[6];

    float* n_out = (float*)d_out;
    float* e_out = n_out + (size_t)BB * NN * DD;

    float* Qw    = (float*)d_ws;                          // 3 x 0.5MB
    float* Kw    = Qw + (size_t)BB * HH * NN * DKK;
    float* Vw    = Kw + (size_t)BB * HH * NN * DKK;
    float* EGw   = Vw + (size_t)BB * HH * NN * DKK;       // 16.8MB
    float* Gpart = EGw + (size_t)BB * HH * NN * NN;       // 64KB

    qkv_kernel<<<BB * NN, 128, 0, stream>>>(n_ptr, W_qkv, Qw, Kw, Vw);
    eg_kernel<<<BB * NN * 2, 256, 0, stream>>>(e, W_g, W_e, O_e, Qw, Kw,
                                               EGw, Gpart, e_out);
    attn_kernel<<<BB * NN, 256, 0, stream>>>(EGw, Gpart, Vw, O_n, n_out);
}

// Round 4
// 314.467 us; speedup vs baseline: 1.0692x; 1.0692x over previous
//
#include <hip/hip_runtime.h>
#include <math.h>

#define BB 2
#define NN 512
#define DD 128
#define HH 8
#define DKK 16
#define TR 64            // tile rows
#define NT (NN / TR)     // 8 tiles per (b,n)

// ---------------- Kernel 1: QKV projection + W_egT staging ----------------
__global__ __launch_bounds__(128)
void qkv_kernel(const float* __restrict__ n_in,
                const float* __restrict__ W_qkv,
                const float* __restrict__ W_g,
                const float* __restrict__ W_e,
                float* __restrict__ Qw, float* __restrict__ Kw,
                float* __restrict__ Vw, float* __restrict__ WegT)
{
    const int bid = blockIdx.x;
    if (bid >= BB * NN) {                    // 16 trailing blocks: WegT[col][d]
        const int col = bid - BB * NN;       // 0..15
        const int t = threadIdx.x;           // 0..127
        WegT[col * DD + t] = (col < 8) ? W_e[t * HH + col]
                                       : W_g[t * HH + (col - 8)];
        return;
    }
    __shared__ float nrow[DD];
    const int bn = bid;
    const int b  = bn >> 9;
    const int nr = bn & 511;
    const int t  = threadIdx.x;
    nrow[t] = n_in[(size_t)bn * DD + t];
    __syncthreads();
    const int h = t >> 4, dk = t & 15;
    const size_t dst = ((size_t)(b * HH + h) * NN + nr) * DKK + dk;
    float accq = 0.f, acck = 0.f, accv = 0.f;
    #pragma unroll 8
    for (int d = 0; d < DD; ++d) {
        const float nv = nrow[d];
        const float* wr = W_qkv + (size_t)d * 3 * DD;
        accq += nv * wr[t];
        acck += nv * wr[t + 128];
        accv += nv * wr[t + 256];
    }
    Qw[dst] = accq;
    Kw[dst] = acck;
    Vw[dst] = accv;
}

// ---------------- Kernel 2: fused E/G + QK + e_out ----------------
// One block per (b,n), 512 threads = 8 waves. Tiles of 64 e-rows staged in
// LDS with XOR swizzle (coalesced global reads, conflict-free LDS reads).
__global__ __launch_bounds__(512, 4)
void eg_kernel(const float* __restrict__ e,
               const float* __restrict__ WegT,
               const float* __restrict__ O_e,
               const float* __restrict__ Qw,
               const float* __restrict__ Kw,
               float* __restrict__ EGw,     // [B*N][H][NN] _E
               float* __restrict__ Gfull,   // [B*N][H] full sigmoid sums
               float* __restrict__ e_out)
{
    __shared__ __align__(16) float4 buf4[TR * 32];   // 32KB swizzled e-tile
    __shared__ __align__(16) float ET[HH * TR];      // 2KB scores tile
    __shared__ __align__(16) float q_lds[DD];        // h-major Q row
    __shared__ __align__(16) float oe_l[HH * DD];    // 4KB O_e

    const int t    = threadIdx.x;
    const int bn   = blockIdx.x;
    const int b    = bn >> 9;
    const int nr   = bn & 511;
    const int wq   = t >> 6;
    const int lane = t & 63;

    if (t < DD)
        q_lds[t] = Qw[((size_t)(b * HH + (t >> 4)) * NN + nr) * DKK + (t & 15)];
    for (int i = t; i < HH * DD; i += 512) oe_l[i] = O_e[i];

    // wave-uniform W columns (scalar-load path via readfirstlane)
    const int c0 = __builtin_amdgcn_readfirstlane(2 * wq);
    const float* __restrict__ w0 = WegT + c0 * DD;
    const float* __restrict__ w1 = w0 + DD;

    const float4* __restrict__ e4 = (const float4*)e + (size_t)bn * NN * 32;

    // prologue: tile 0 -> regs -> swizzled LDS
    float4 st[4];
    #pragma unroll
    for (int j = 0; j < 4; ++j) st[j] = e4[j * 512 + t];
    #pragma unroll
    for (int j = 0; j < 4; ++j) {
        const int i = j * 512 + t;
        const int r = i >> 5, c4 = i & 31;
        buf4[r * 32 + (c4 ^ (r & 31))] = st[j];
    }

    float gacc0 = 0.f, gacc1 = 0.f;

    for (int tt = 0; tt < NT; ++tt) {
        __syncthreads();   // buf writes visible; prev e_out done with ET

        if (tt + 1 < NT) { // prefetch next tile into regs (hides under Phase A)
            #pragma unroll
            for (int j = 0; j < 4; ++j)
                st[j] = e4[(tt + 1) * 2048 + j * 512 + t];
        }

        // ---- Phase A: row = lane; 2 cols per wave ----
        float a0 = 0.f, a1 = 0.f;
        #pragma unroll
        for (int d16 = 0; d16 < 8; ++d16) {
            #pragma unroll
            for (int k = 0; k < 4; ++k) {
                const float4 ev = buf4[lane * 32 + ((d16 * 4 + k) ^ (lane & 31))];
                const float4 wa = *(const float4*)&w0[d16 * 16 + k * 4];
                const float4 wb = *(const float4*)&w1[d16 * 16 + k * 4];
                a0 += ev.x * wa.x + ev.y * wa.y + ev.z * wa.z + ev.w * wa.w;
                a1 += ev.x * wb.x + ev.y * wb.y + ev.z * wb.z + ev.w * wb.w;
            }
        }
        if (wq < 4) {
            ET[(2 * wq)     * TR + lane] = a0;
            ET[(2 * wq + 1) * TR + lane] = a1;
        } else {
            gacc0 += 1.f / (1.f + __expf(-a0));
            gacc1 += 1.f / (1.f + __expf(-a1));
        }
        __syncthreads();   // ET ready; buf reads done; prefetch drained

        if (tt + 1 < NT) { // refill LDS with next tile (swizzled)
            #pragma unroll
            for (int j = 0; j < 4; ++j) {
                const int i = j * 512 + t;
                const int r = i >> 5, c4 = i & 31;
                buf4[r * 32 + (c4 ^ (r & 31))] = st[j];
            }
        }

        // ---- QK: h = wq, m = tt*64 + lane ----
        {
            const int h = wq;
            const int m = tt * TR + lane;
            const float4* __restrict__ kb =
                (const float4*)Kw + ((size_t)(b * HH + h) * NN + m) * 4;
            const float4 k0 = kb[0], k1 = kb[1], k2 = kb[2], k3 = kb[3];
            const float4 q0 = *(const float4*)&q_lds[h * 16 + 0];
            const float4 q1 = *(const float4*)&q_lds[h * 16 + 4];
            const float4 q2 = *(const float4*)&q_lds[h * 16 + 8];
            const float4 q3 = *(const float4*)&q_lds[h * 16 + 12];
            float s = q0.x*k0.x + q0.y*k0.y + q0.z*k0.z + q0.w*k0.w
                    + q1.x*k1.x + q1.y*k1.y + q1.z*k1.z + q1.w*k1.w
                    + q2.x*k2.x + q2.y*k2.y + q2.z*k2.z + q2.w*k2.w
                    + q3.x*k3.x + q3.y*k3.y + q3.z*k3.z + q3.w*k3.w;
            s *= 0.25f;
            s = fminf(5.f, fmaxf(-5.f, s));
            const float val = s + ET[h * TR + lane];
            ET[h * TR + lane] = val;
            EGw[((size_t)bn * HH + h) * NN + m] = val;
        }
        __syncthreads();   // _E tile ready

        // ---- e_out tile: c4 fixed per thread, 4 m-rows ----
        {
            const int c4o = t & 31;
            const int m0  = t >> 5;   // 0..15
            float4* __restrict__ out4 =
                (float4*)e_out + ((size_t)bn * NN + tt * TR) * 32;
            #pragma unroll
            for (int it = 0; it < 4; ++it) {
                const int m = m0 + it * 16;
                float4 r{0.f, 0.f, 0.f, 0.f};
                #pragma unroll
                for (int h = 0; h < HH; ++h) {
                    const float evv = ET[h * TR + m];
                    const float4 oe = *(const float4*)&oe_l[h * DD + c4o * 4];
                    r.x += evv * oe.x;
                    r.y += evv * oe.y;
                    r.z += evv * oe.z;
                    r.w += evv * oe.w;
                }
                out4[m * 32 + c4o] = r;
            }
        }
    }

    // ---- final G reduction (waves 4..7 own cols 0..7 of G) ----
    if (wq >= 4) {
        #pragma unroll
        for (int off = 32; off >= 1; off >>= 1) {
            gacc0 += __shfl_xor(gacc0, off, 64);
            gacc1 += __shfl_xor(gacc1, off, 64);
        }
        if (lane == 0) {
            Gfull[(size_t)bn * HH + (2 * wq - 8)] = gacc0;
            Gfull[(size_t)bn * HH + (2 * wq - 7)] = gacc1;
        }
    }
}

// ---------------- Kernel 3: softmax + AV + n_out ----------------
__global__ __launch_bounds__(256)
void attn_kernel(const float* __restrict__ EGw,
                 const float* __restrict__ Gfull,
                 const float* __restrict__ Vw,
                 const float* __restrict__ O_n,
                 float* __restrict__ n_out)
{
    __shared__ __align__(16) float ET[HH * NN];   // 16KB
    __shared__ __align__(16) float vout[DD];
    __shared__ float dc[HH];

    const int t    = threadIdx.x;
    const int bn   = blockIdx.x;
    const int b    = bn >> 9;
    const int wq   = t >> 6;
    const int lane = t & 63;

    const float4* __restrict__ eg4 = (const float4*)(EGw + (size_t)bn * HH * NN);
    float4* et4 = (float4*)ET;
    #pragma unroll
    for (int i = t; i < HH * NN / 4; i += 256) et4[i] = eg4[i];
    if (t < HH) dc[t] = log1pf(Gfull[(size_t)bn * HH + t]);
    __syncthreads();

    #pragma unroll 1
    for (int hw = 0; hw < 2; ++hw) {
        const int h = wq * 2 + hw;
        float vals[8];
        float rmax = -1e30f;
        #pragma unroll
        for (int k = 0; k < 8; ++k) {
            vals[k] = ET[h * NN + k * 64 + lane];
            rmax = fmaxf(rmax, vals[k]);
        }
        #pragma unroll
        for (int off = 32; off >= 1; off >>= 1)
            rmax = fmaxf(rmax, __shfl_xor(rmax, off, 64));
        float sum = 0.f;
        #pragma unroll
        for (int k = 0; k < 8; ++k) sum += __expf(vals[k] - rmax);
        #pragma unroll
        for (int off = 32; off >= 1; off >>= 1)
            sum += __shfl_xor(sum, off, 64);
        const float factor = dc[h] / sum;

        const int ddx = lane & 15, mg = lane >> 4;
        const float* __restrict__ vb = Vw + ((size_t)(b * HH + h) * NN) * DKK;
        float av = 0.f;
        #pragma unroll 4
        for (int m = mg; m < NN; m += 4) {
            const float p = __expf(ET[h * NN + m] - rmax);
            av += p * vb[m * DKK + ddx];
        }
        av += __shfl_xor(av, 16, 64);
        av += __shfl_xor(av, 32, 64);
        if (mg == 0) vout[h * DKK + ddx] = av * factor;
    }
    __syncthreads();

    if (t < DD) {
        float a3 = 0.f;
        #pragma unroll 4
        for (int d = 0; d < DD; ++d) a3 += vout[d] * O_n[d * DD + t];
        n_out[(size_t)bn * DD + t] = a3;
    }
}

extern "C" void kernel_launch(void* const* d_in, const int* in_sizes, int n_in,
                              void* d_out, int out_size, void* d_ws, size_t ws_size,
                              hipStream_t stream)
{
    const float* n_ptr = (const float*)d_in[0];
    const float* e     = (const float*)d_in[1];
    const float* W_qkv = (const float*)d_in[2];
    const float* O_n   = (const float*)d_in[3];
    const float* W_g   = (const float*)d_in[4];
    const float* W_e   = (const float*)d_in[5];
    const float* O_e   = (const float*)d_in[6];

    float* n_out = (float*)d_out;
    float* e_out = n_out + (size_t)BB * NN * DD;

    float* Qw    = (float*)d_ws;                          // 3 x 0.5MB
    float* Kw    = Qw + (size_t)BB * HH * NN * DKK;
    float* Vw    = Kw + (size_t)BB * HH * NN * DKK;
    float* EGw   = Vw + (size_t)BB * HH * NN * DKK;       // 16.8MB
    float* Gfull = EGw + (size_t)BB * HH * NN * NN;       // 32KB
    float* WegT  = Gfull + (size_t)BB * NN * HH;          // 8KB

    qkv_kernel<<<BB * NN + 16, 128, 0, stream>>>(n_ptr, W_qkv, W_g, W_e,
                                                 Qw, Kw, Vw, WegT);
    eg_kernel<<<BB * NN, 512, 0, stream>>>(e, WegT, O_e, Qw, Kw,
                                           EGw, Gfull, e_out);
    attn_kernel<<<BB * NN, 256, 0, stream>>>(EGw, Gfull, Vw, O_n, n_out);
}

// Round 5
// 257.323 us; speedup vs baseline: 1.3067x; 1.2221x over previous
//
#include <hip/hip_runtime.h>
#include <math.h>

#define BB 2
#define NN 512
#define DD 128
#define HH 8
#define DKK 16
#define TR 64            // tile rows
#define NT (NN / TR)     // 8 tiles per (b,n)

// ---------------- Kernel 1: QKV projection + W_egT staging ----------------
__global__ __launch_bounds__(128)
void qkv_kernel(const float* __restrict__ n_in,
                const float* __restrict__ W_qkv,
                const float* __restrict__ W_g,
                const float* __restrict__ W_e,
                float* __restrict__ Qw, float* __restrict__ Kw,
                float* __restrict__ Vw, float* __restrict__ WegT)
{
    const int bid = blockIdx.x;
    if (bid >= BB * NN) {                    // 16 trailing blocks: WegT[col][d]
        const int col = bid - BB * NN;       // 0..15
        const int t = threadIdx.x;           // 0..127
        WegT[col * DD + t] = (col < 8) ? W_e[t * HH + col]
                                       : W_g[t * HH + (col - 8)];
        return;
    }
    __shared__ float nrow[DD];
    const int bn = bid;
    const int b  = bn >> 9;
    const int nr = bn & 511;
    const int t  = threadIdx.x;
    nrow[t] = n_in[(size_t)bn * DD + t];
    __syncthreads();
    const int h = t >> 4, dk = t & 15;
    const size_t dst = ((size_t)(b * HH + h) * NN + nr) * DKK + dk;
    float accq = 0.f, acck = 0.f, accv = 0.f;
    #pragma unroll 8
    for (int d = 0; d < DD; ++d) {
        const float nv = nrow[d];
        const float* wr = W_qkv + (size_t)d * 3 * DD;
        accq += nv * wr[t];
        acck += nv * wr[t + 128];
        accv += nv * wr[t + 256];
    }
    Qw[dst] = accq;
    Kw[dst] = acck;
    Vw[dst] = accv;
}

// ---------------- Kernel 1b: QKc = clamp(Q K^T * scale) ----------------
// grid = B*H*16 blocks (32 q-rows each), 256 threads. K[b,h] staged in LDS.
__global__ __launch_bounds__(256)
void qk_kernel(const float* __restrict__ Qw,
               const float* __restrict__ Kw,
               float* __restrict__ QKc)      // [B*N][H][NN]
{
    __shared__ __align__(16) float4 Kl[NN * 4];   // 32KB  [m][4]
    __shared__ __align__(16) float4 Ql[32 * 4];   // 2KB   [qr][4]

    const int bid = blockIdx.x;
    const int qt  = bid & 15;
    const int h   = (bid >> 4) & 7;
    const int b   = bid >> 7;
    const int t   = threadIdx.x;

    const float4* __restrict__ kb =
        (const float4*)Kw + ((size_t)(b * HH + h) * NN) * 4;
    #pragma unroll
    for (int j = 0; j < 8; ++j) Kl[j * 256 + t] = kb[j * 256 + t];
    if (t < 128)
        Ql[t] = ((const float4*)Qw)[((size_t)(b * HH + h) * NN + qt * 32) * 4 + t];
    __syncthreads();

    const int qr = t >> 3;        // 0..31
    const int mq = t & 7;         // 0..7 -> 64 m's each
    const float4 q0 = Ql[qr * 4 + 0];
    const float4 q1 = Ql[qr * 4 + 1];
    const float4 q2 = Ql[qr * 4 + 2];
    const float4 q3 = Ql[qr * 4 + 3];

    float4* __restrict__ out4 =
        (float4*)QKc + (((size_t)(b * NN + qt * 32 + qr) * HH + h) * NN) / 4;

    #pragma unroll 1
    for (int c = 0; c < 16; ++c) {           // 16 float4 stores of 4 m's
        float4 r;
        float* rp = (float*)&r;
        #pragma unroll
        for (int i = 0; i < 4; ++i) {
            const int m = mq * 64 + c * 4 + i;
            const float4 k0 = Kl[m * 4 + 0];
            const float4 k1 = Kl[m * 4 + 1];
            const float4 k2 = Kl[m * 4 + 2];
            const float4 k3 = Kl[m * 4 + 3];
            float s = q0.x*k0.x + q0.y*k0.y + q0.z*k0.z + q0.w*k0.w
                    + q1.x*k1.x + q1.y*k1.y + q1.z*k1.z + q1.w*k1.w
                    + q2.x*k2.x + q2.y*k2.y + q2.z*k2.z + q2.w*k2.w
                    + q3.x*k3.x + q3.y*k3.y + q3.z*k3.z + q3.w*k3.w;
            s *= 0.25f;
            rp[i] = fminf(5.f, fmaxf(-5.f, s));
        }
        out4[mq * 16 + c] = r;
    }
}

// ---------------- Kernel 2: fused E/G + (+QKc) + e_out ----------------
// One block per (b,n), 512 threads = 8 waves. Inner loop has NO global loads
// except the e-tile prefetch (clean vmcnt FIFO, no spill pressure).
__global__ __launch_bounds__(512)
void eg_kernel(const float* __restrict__ e,
               const float* __restrict__ WegT,
               const float* __restrict__ O_e,
               const float* __restrict__ QKc,
               float* __restrict__ EGw,     // [B*N][H][NN] _E
               float* __restrict__ Gfull,   // [B*N][H]
               float* __restrict__ e_out)
{
    __shared__ __align__(16) float4 buf4[TR * 32];   // 32KB swizzled e-tile
    __shared__ __align__(16) float W_lds[16 * DD];   // 8KB
    __shared__ __align__(16) float ET[HH * TR];      // 2KB

    const int t    = threadIdx.x;
    const int bn   = blockIdx.x;
    const int wq   = t >> 6;
    const int lane = t & 63;

    for (int i = t; i < 16 * DD; i += 512) W_lds[i] = WegT[i];

    // per-thread O_e column cache (c4o fixed)
    const int c4o = t & 31;
    const int m0  = t >> 5;     // 0..15
    float4 oe[8];
    #pragma unroll
    for (int h = 0; h < 8; ++h)
        oe[h] = ((const float4*)O_e)[h * 32 + c4o];

    // per-wave QKc row (head = wq), one value per tile per lane
    float qkc[NT];
    #pragma unroll
    for (int tt = 0; tt < NT; ++tt)
        qkc[tt] = QKc[((size_t)bn * HH + wq) * NN + tt * TR + lane];

    // wave-uniform W column pointers (cols 2wq, 2wq+1)
    const float* __restrict__ w0 = &W_lds[(2 * wq) * DD];
    const float* __restrict__ w1 = w0 + DD;

    const float4* __restrict__ e4 = (const float4*)e + (size_t)bn * NN * 32;

    // prologue: tile 0 -> regs -> swizzled LDS
    float4 st[4];
    #pragma unroll
    for (int j = 0; j < 4; ++j) st[j] = e4[j * 512 + t];
    #pragma unroll
    for (int j = 0; j < 4; ++j) {
        const int i = j * 512 + t;
        const int r = i >> 5, x = i & 31;
        buf4[r * 32 + (x ^ (r & 31))] = st[j];
    }

    float ga0 = 0.f, ga1 = 0.f;

    for (int tt = 0; tt < NT; ++tt) {
        __syncthreads();   // buf ready; prev ET consumed

        if (tt + 1 < NT) { // prefetch next tile into regs
            #pragma unroll
            for (int j = 0; j < 4; ++j)
                st[j] = e4[(tt + 1) * 2048 + j * 512 + t];
        }

        // ---- Phase A: row = lane; 2 cols per wave ----
        float a0 = 0.f, a1 = 0.f;
        #pragma unroll
        for (int c = 0; c < 32; ++c) {
            const float4 ev = buf4[lane * 32 + (c ^ (lane & 31))];
            const float4 wa = *(const float4*)&w0[c * 4];
            const float4 wb = *(const float4*)&w1[c * 4];
            a0 += ev.x * wa.x + ev.y * wa.y + ev.z * wa.z + ev.w * wa.w;
            a1 += ev.x * wb.x + ev.y * wb.y + ev.z * wb.z + ev.w * wb.w;
        }
        if (wq < 4) {
            ET[(2 * wq)     * TR + lane] = a0;
            ET[(2 * wq + 1) * TR + lane] = a1;
        } else {
            ga0 += 1.f / (1.f + __expf(-a0));
            ga1 += 1.f / (1.f + __expf(-a1));
        }
        __syncthreads();   // ET ready; buf consumed; prefetch drained

        if (tt + 1 < NT) { // refill LDS (swizzled)
            #pragma unroll
            for (int j = 0; j < 4; ++j) {
                const int i = j * 512 + t;
                const int r = i >> 5, x = i & 31;
                buf4[r * 32 + (x ^ (r & 31))] = st[j];
            }
        }

        // ---- Phase B: _E = E + qkc ; wave wq owns head wq ----
        {
            const float val = ET[wq * TR + lane] + qkc[tt];
            ET[wq * TR + lane] = val;
            EGw[((size_t)bn * HH + wq) * NN + tt * TR + lane] = val;
        }
        __syncthreads();   // _E tile final

        // ---- Phase C: e_out tile ----
        float4* __restrict__ out4 =
            (float4*)e_out + ((size_t)bn * NN + tt * TR) * 32;
        #pragma unroll
        for (int it = 0; it < 4; ++it) {
            const int m = m0 + it * 16;
            float4 r{0.f, 0.f, 0.f, 0.f};
            #pragma unroll
            for (int h = 0; h < HH; ++h) {
                const float evv = ET[h * TR + m];
                r.x += evv * oe[h].x;
                r.y += evv * oe[h].y;
                r.z += evv * oe[h].z;
                r.w += evv * oe[h].w;
            }
            out4[m * 32 + c4o] = r;
        }
    }

    // ---- final G reduction (waves 4..7 own G cols 2(wq-4), +1) ----
    if (wq >= 4) {
        #pragma unroll
        for (int off = 32; off >= 1; off >>= 1) {
            ga0 += __shfl_xor(ga0, off, 64);
            ga1 += __shfl_xor(ga1, off, 64);
        }
        if (lane == 0) {
            Gfull[(size_t)bn * HH + 2 * (wq - 4)]     = ga0;
            Gfull[(size_t)bn * HH + 2 * (wq - 4) + 1] = ga1;
        }
    }
}

// ---------------- Kernel 3: softmax + AV + n_out ----------------
__global__ __launch_bounds__(256)
void attn_kernel(const float* __restrict__ EGw,
                 const float* __restrict__ Gfull,
                 const float* __restrict__ Vw,
                 const float* __restrict__ O_n,
                 float* __restrict__ n_out)
{
    __shared__ __align__(16) float ET[HH * NN];   // 16KB
    __shared__ __align__(16) float vout[DD];
    __shared__ float dc[HH];

    const int t    = threadIdx.x;
    const int bn   = blockIdx.x;
    const int b    = bn >> 9;
    const int wq   = t >> 6;
    const int lane = t & 63;

    const float4* __restrict__ eg4 = (const float4*)(EGw + (size_t)bn * HH * NN);
    float4* et4 = (float4*)ET;
    #pragma unroll
    for (int i = t; i < HH * NN / 4; i += 256) et4[i] = eg4[i];
    if (t < HH) dc[t] = log1pf(Gfull[(size_t)bn * HH + t]);
    __syncthreads();

    #pragma unroll 1
    for (int hw = 0; hw < 2; ++hw) {
        const int h = wq * 2 + hw;
        float vals[8];
        float rmax = -1e30f;
        #pragma unroll
        for (int k = 0; k < 8; ++k) {
            vals[k] = ET[h * NN + k * 64 + lane];
            rmax = fmaxf(rmax, vals[k]);
        }
        #pragma unroll
        for (int off = 32; off >= 1; off >>= 1)
            rmax = fmaxf(rmax, __shfl_xor(rmax, off, 64));
        float sum = 0.f;
        #pragma unroll
        for (int k = 0; k < 8; ++k) sum += __expf(vals[k] - rmax);
        #pragma unroll
        for (int off = 32; off >= 1; off >>= 1)
            sum += __shfl_xor(sum, off, 64);
        const float factor = dc[h] / sum;

        const int ddx = lane & 15, mg = lane >> 4;
        const float* __restrict__ vb = Vw + ((size_t)(b * HH + h) * NN) * DKK;
        float av = 0.f;
        #pragma unroll 4
        for (int m = mg; m < NN; m += 4) {
            const float p = __expf(ET[h * NN + m] - rmax);
            av += p * vb[m * DKK + ddx];
        }
        av += __shfl_xor(av, 16, 64);
        av += __shfl_xor(av, 32, 64);
        if (mg == 0) vout[h * DKK + ddx] = av * factor;
    }
    __syncthreads();

    if (t < DD) {
        float a3 = 0.f;
        #pragma unroll 4
        for (int d = 0; d < DD; ++d) a3 += vout[d] * O_n[d * DD + t];
        n_out[(size_t)bn * DD + t] = a3;
    }
}

extern "C" void kernel_launch(void* const* d_in, const int* in_sizes, int n_in,
                              void* d_out, int out_size, void* d_ws, size_t ws_size,
                              hipStream_t stream)
{
    const float* n_ptr = (const float*)d_in[0];
    const float* e     = (const float*)d_in[1];
    const float* W_qkv = (const float*)d_in[2];
    const float* O_n   = (const float*)d_in[3];
    const float* W_g   = (const float*)d_in[4];
    const float* W_e   = (const float*)d_in[5];
    const float* O_e   = (const float*)d_in[6];

    float* n_out = (float*)d_out;
    float* e_out = n_out + (size_t)BB * NN * DD;

    float* Qw    = (float*)d_ws;                          // 3 x 0.5MB
    float* Kw    = Qw + (size_t)BB * HH * NN * DKK;
    float* Vw    = Kw + (size_t)BB * HH * NN * DKK;
    float* EGw   = Vw + (size_t)BB * HH * NN * DKK;       // 16.8MB
    float* QKc   = EGw + (size_t)BB * HH * NN * NN;       // 16.8MB
    float* Gfull = QKc + (size_t)BB * HH * NN * NN;       // 32KB
    float* WegT  = Gfull + (size_t)BB * NN * HH;          // 8KB

    qkv_kernel<<<BB * NN + 16, 128, 0, stream>>>(n_ptr, W_qkv, W_g, W_e,
                                                 Qw, Kw, Vw, WegT);
    qk_kernel<<<BB * HH * 16, 256, 0, stream>>>(Qw, Kw, QKc);
    eg_kernel<<<BB * NN, 512, 0, stream>>>(e, WegT, O_e, QKc,
                                           EGw, Gfull, e_out);
    attn_kernel<<<BB * NN, 256, 0, stream>>>(EGw, Gfull, Vw, O_n, n_out);
}

// Round 6
// 211.210 us; speedup vs baseline: 1.5920x; 1.2183x over previous
//
#include <hip/hip_runtime.h>
#include <math.h>

#define BB 2
#define NN 512
#define DD 128
#define HH 8
#define DKK 16
#define TR 64            // tile rows
#define NT (NN / TR)     // 8 tiles per (b,n)

// direct global->LDS 16B DMA (dest = wave-uniform base + lane*16)
#define GL_LDS16(gp, lp)                                                     \
    __builtin_amdgcn_global_load_lds(                                        \
        (const __attribute__((address_space(1))) void*)(gp),                 \
        (__attribute__((address_space(3))) void*)(lp), 16, 0, 0)

// ---------------- Kernel 1: QKV projection + W_egT staging ----------------
__global__ __launch_bounds__(128)
void qkv_kernel(const float* __restrict__ n_in,
                const float* __restrict__ W_qkv,
                const float* __restrict__ W_g,
                const float* __restrict__ W_e,
                float* __restrict__ Qw, float* __restrict__ Kw,
                float* __restrict__ Vw, float* __restrict__ WegT)
{
    const int bid = blockIdx.x;
    if (bid >= BB * NN) {                    // 16 trailing blocks: WegT[col][d]
        const int col = bid - BB * NN;       // 0..15
        const int t = threadIdx.x;           // 0..127
        WegT[col * DD + t] = (col < 8) ? W_e[t * HH + col]
                                       : W_g[t * HH + (col - 8)];
        return;
    }
    __shared__ float nrow[DD];
    const int bn = bid;
    const int b  = bn >> 9;
    const int nr = bn & 511;
    const int t  = threadIdx.x;
    nrow[t] = n_in[(size_t)bn * DD + t];
    __syncthreads();
    const int h = t >> 4, dk = t & 15;
    const size_t dst = ((size_t)(b * HH + h) * NN + nr) * DKK + dk;
    float accq = 0.f, acck = 0.f, accv = 0.f;
    #pragma unroll 8
    for (int d = 0; d < DD; ++d) {
        const float nv = nrow[d];
        const float* wr = W_qkv + (size_t)d * 3 * DD;
        accq += nv * wr[t];
        acck += nv * wr[t + 128];
        accv += nv * wr[t + 256];
    }
    Qw[dst] = accq;
    Kw[dst] = acck;
    Vw[dst] = accv;
}

// ---------------- Kernel 1b: QKc = clamp(Q K^T * scale) ----------------
__global__ __launch_bounds__(256)
void qk_kernel(const float* __restrict__ Qw,
               const float* __restrict__ Kw,
               float* __restrict__ QKc)      // [B*N][H][NN]
{
    __shared__ __align__(16) float4 Kl[NN * 4];   // 32KB  [m][4]
    __shared__ __align__(16) float4 Ql[32 * 4];   // 2KB   [qr][4]

    const int bid = blockIdx.x;
    const int qt  = bid & 15;
    const int h   = (bid >> 4) & 7;
    const int b   = bid >> 7;
    const int t   = threadIdx.x;

    const float4* __restrict__ kb =
        (const float4*)Kw + ((size_t)(b * HH + h) * NN) * 4;
    #pragma unroll
    for (int j = 0; j < 8; ++j) Kl[j * 256 + t] = kb[j * 256 + t];
    if (t < 128)
        Ql[t] = ((const float4*)Qw)[((size_t)(b * HH + h) * NN + qt * 32) * 4 + t];
    __syncthreads();

    const int qr = t >> 3;        // 0..31
    const int mq = t & 7;         // 0..7 -> 64 m's each
    const float4 q0 = Ql[qr * 4 + 0];
    const float4 q1 = Ql[qr * 4 + 1];
    const float4 q2 = Ql[qr * 4 + 2];
    const float4 q3 = Ql[qr * 4 + 3];

    float4* __restrict__ out4 =
        (float4*)QKc + (((size_t)(b * NN + qt * 32 + qr) * HH + h) * NN) / 4;

    #pragma unroll 1
    for (int c = 0; c < 16; ++c) {
        float4 r;
        float* rp = (float*)&r;
        #pragma unroll
        for (int i = 0; i < 4; ++i) {
            const int m = mq * 64 + c * 4 + i;
            const float4 k0 = Kl[m * 4 + 0];
            const float4 k1 = Kl[m * 4 + 1];
            const float4 k2 = Kl[m * 4 + 2];
            const float4 k3 = Kl[m * 4 + 3];
            float s = q0.x*k0.x + q0.y*k0.y + q0.z*k0.z + q0.w*k0.w
                    + q1.x*k1.x + q1.y*k1.y + q1.z*k1.z + q1.w*k1.w
                    + q2.x*k2.x + q2.y*k2.y + q2.z*k2.z + q2.w*k2.w
                    + q3.x*k3.x + q3.y*k3.y + q3.z*k3.z + q3.w*k3.w;
            s *= 0.25f;
            rp[i] = fminf(5.f, fmaxf(-5.f, s));
        }
        out4[mq * 16 + c] = r;
    }
}

// ---------------- Kernel 2: fused E/G + (+QKc) + e_out ----------------
// One block per (b,n), 512 threads = 8 waves. Double-buffered global_load_lds
// staging with pre-swizzled source addresses; raw barriers + counted vmcnt.
__global__ __launch_bounds__(512, 2)
void eg_kernel(const float* __restrict__ e,
               const float* __restrict__ WegT,
               const float* __restrict__ O_e,
               const float* __restrict__ QKc,
               float* __restrict__ EGw,     // [B*N][H][NN] _E
               float* __restrict__ Gfull,   // [B*N][H]
               float* __restrict__ e_out)
{
    __shared__ __align__(16) float4 buf4[2][TR * 32];  // 2 x 32KB e-tiles
    __shared__ __align__(16) float W_lds[16 * DD];     // 8KB
    __shared__ __align__(16) float ET_t[TR][HH];       // 2KB [m][h]

    const int t    = threadIdx.x;
    const int bn   = blockIdx.x;
    const int wq   = t >> 6;
    const int lane = t & 63;
    const int c4o  = t & 31;
    const int m0   = t >> 5;     // 0..15

    // ---- prologue ----
    for (int i = t; i < 16 * DD; i += 512) W_lds[i] = WegT[i];

    float4 oe[8];                 // O_e column cache (c4o fixed per thread)
    #pragma unroll
    for (int h = 0; h < 8; ++h)
        oe[h] = ((const float4*)O_e)[h * 32 + c4o];

    // QKc rows for this wave's two heads (waves 0-3), fully static -> regs
    float qk0[NT], qk1[NT];
    if (wq < 4) {
        const float* qb = QKc + ((size_t)bn * HH + 2 * wq) * NN + lane;
        #pragma unroll
        for (int j = 0; j < NT; ++j) {
            qk0[j] = qb[j * TR];
            qk1[j] = qb[NN + j * TR];
        }
    }

    const float* __restrict__ w0 = &W_lds[(2 * wq) * DD];
    const float* __restrict__ w1 = w0 + DD;

    const float4* __restrict__ e4 = (const float4*)e + (size_t)bn * NN * 32;

    // issue tile 0 into buf[0] (pre-swizzled global source, linear LDS dest)
    {
        const int x = t & 31;
        #pragma unroll
        for (int j = 0; j < 4; ++j) {
            const int r = (j * 512 + t) >> 5;
            GL_LDS16(e4 + r * 32 + (x ^ (r & 31)),
                     &buf4[0][j * 512 + (t & ~63)]);
        }
    }
    asm volatile("s_waitcnt vmcnt(0)" ::: "memory");
    asm volatile("s_waitcnt lgkmcnt(0)" ::: "memory");
    __builtin_amdgcn_s_barrier();

    float ga0 = 0.f, ga1 = 0.f;

    #pragma unroll
    for (int tt = 0; tt < NT; ++tt) {
        // issue next tile into the buffer all waves finished reading last iter
        if (tt + 1 < NT) {
            const int x = t & 31;
            #pragma unroll
            for (int j = 0; j < 4; ++j) {
                const int r = (j * 512 + t) >> 5;
                GL_LDS16(e4 + (size_t)(tt + 1) * 2048 + r * 32 + (x ^ (r & 31)),
                         &buf4[(tt + 1) & 1][j * 512 + (t & ~63)]);
            }
            asm volatile("s_waitcnt vmcnt(8)" ::: "memory");
        } else {
            asm volatile("s_waitcnt vmcnt(4)" ::: "memory");
        }
        __builtin_amdgcn_s_barrier();   // buf[tt&1] fully loaded for all waves

        // ---- Phase A: row = lane; 2 W-cols per wave ----
        const float4* __restrict__ bcur = buf4[tt & 1];
        float a0 = 0.f, a1 = 0.f;
        #pragma unroll
        for (int c = 0; c < 32; ++c) {
            const float4 ev = bcur[(lane << 5) + (c ^ (lane & 31))];
            const float4 wa = *(const float4*)&w0[c * 4];
            const float4 wb = *(const float4*)&w1[c * 4];
            a0 += ev.x * wa.x + ev.y * wa.y + ev.z * wa.z + ev.w * wa.w;
            a1 += ev.x * wb.x + ev.y * wb.y + ev.z * wb.z + ev.w * wb.w;
        }
        if (wq < 4) {
            const int h0 = 2 * wq, h1 = h0 + 1;
            const float v0 = a0 + qk0[tt];
            const float v1 = a1 + qk1[tt];
            ET_t[lane][h0] = v0;
            ET_t[lane][h1] = v1;
            EGw[((size_t)bn * HH + h0) * NN + tt * TR + lane] = v0;
            EGw[((size_t)bn * HH + h1) * NN + tt * TR + lane] = v1;
        } else {
            ga0 += 1.f / (1.f + __expf(-a0));
            ga1 += 1.f / (1.f + __expf(-a1));
        }
        asm volatile("s_waitcnt lgkmcnt(0)" ::: "memory");
        __builtin_amdgcn_s_barrier();   // ET_t final

        // ---- Phase C: e_out tile ----
        float4* __restrict__ out4 =
            (float4*)e_out + ((size_t)bn * NN + tt * TR) * 32;
        #pragma unroll
        for (int it = 0; it < 4; ++it) {
            const int m = m0 + it * 16;
            const float4 elo = *(const float4*)&ET_t[m][0];
            const float4 ehi = *(const float4*)&ET_t[m][4];
            float4 r;
            r.x = elo.x*oe[0].x + elo.y*oe[1].x + elo.z*oe[2].x + elo.w*oe[3].x
                + ehi.x*oe[4].x + ehi.y*oe[5].x + ehi.z*oe[6].x + ehi.w*oe[7].x;
            r.y = elo.x*oe[0].y + elo.y*oe[1].y + elo.z*oe[2].y + elo.w*oe[3].y
                + ehi.x*oe[4].y + ehi.y*oe[5].y + ehi.z*oe[6].y + ehi.w*oe[7].y;
            r.z = elo.x*oe[0].z + elo.y*oe[1].z + elo.z*oe[2].z + elo.w*oe[3].z
                + ehi.x*oe[4].z + ehi.y*oe[5].z + ehi.z*oe[6].z + ehi.w*oe[7].z;
            r.w = elo.x*oe[0].w + elo.y*oe[1].w + elo.z*oe[2].w + elo.w*oe[3].w
                + ehi.x*oe[4].w + ehi.y*oe[5].w + ehi.z*oe[6].w + ehi.w*oe[7].w;
            out4[m * 32 + c4o] = r;
        }
    }

    // ---- final G reduction (waves 4..7 own G cols 2(wq-4), +1) ----
    if (wq >= 4) {
        #pragma unroll
        for (int off = 32; off >= 1; off >>= 1) {
            ga0 += __shfl_xor(ga0, off, 64);
            ga1 += __shfl_xor(ga1, off, 64);
        }
        if (lane == 0) {
            Gfull[(size_t)bn * HH + 2 * (wq - 4)]     = ga0;
            Gfull[(size_t)bn * HH + 2 * (wq - 4) + 1] = ga1;
        }
    }
}

// ---------------- Kernel 3: softmax + AV + n_out ----------------
__global__ __launch_bounds__(256)
void attn_kernel(const float* __restrict__ EGw,
                 const float* __restrict__ Gfull,
                 const float* __restrict__ Vw,
                 const float* __restrict__ O_n,
                 float* __restrict__ n_out)
{
    __shared__ __align__(16) float ET[HH * NN];   // 16KB
    __shared__ __align__(16) float vout[DD];
    __shared__ float dc[HH];

    const int t    = threadIdx.x;
    const int bn   = blockIdx.x;
    const int b    = bn >> 9;
    const int wq   = t >> 6;
    const int lane = t & 63;

    const float4* __restrict__ eg4 = (const float4*)(EGw + (size_t)bn * HH * NN);
    float4* et4 = (float4*)ET;
    #pragma unroll
    for (int i = t; i < HH * NN / 4; i += 256) et4[i] = eg4[i];
    if (t < HH) dc[t] = log1pf(Gfull[(size_t)bn * HH + t]);
    __syncthreads();

    #pragma unroll 1
    for (int hw = 0; hw < 2; ++hw) {
        const int h = wq * 2 + hw;
        float vals[8];
        float rmax = -1e30f;
        #pragma unroll
        for (int k = 0; k < 8; ++k) {
            vals[k] = ET[h * NN + k * 64 + lane];
            rmax = fmaxf(rmax, vals[k]);
        }
        #pragma unroll
        for (int off = 32; off >= 1; off >>= 1)
            rmax = fmaxf(rmax, __shfl_xor(rmax, off, 64));
        float sum = 0.f;
        #pragma unroll
        for (int k = 0; k < 8; ++k) sum += __expf(vals[k] - rmax);
        #pragma unroll
        for (int off = 32; off >= 1; off >>= 1)
            sum += __shfl_xor(sum, off, 64);
        const float factor = dc[h] / sum;

        const int ddx = lane & 15, mg = lane >> 4;
        const float* __restrict__ vb = Vw + ((size_t)(b * HH + h) * NN) * DKK;
        float av = 0.f;
        #pragma unroll 4
        for (int m = mg; m < NN; m += 4) {
            const float p = __expf(ET[h * NN + m] - rmax);
            av += p * vb[m * DKK + ddx];
        }
        av += __shfl_xor(av, 16, 64);
        av += __shfl_xor(av, 32, 64);
        if (mg == 0) vout[h * DKK + ddx] = av * factor;
    }
    __syncthreads();

    if (t < DD) {
        float a3 = 0.f;
        #pragma unroll 4
        for (int d = 0; d < DD; ++d) a3 += vout[d] * O_n[d * DD + t];
        n_out[(size_t)bn * DD + t] = a3;
    }
}

extern "C" void kernel_launch(void* const* d_in, const int* in_sizes, int n_in,
                              void* d_out, int out_size, void* d_ws, size_t ws_size,
                              hipStream_t stream)
{
    const float* n_ptr = (const float*)d_in[0];
    const float* e     = (const float*)d_in[1];
    const float* W_qkv = (const float*)d_in[2];
    const float* O_n   = (const float*)d_in[3];
    const float* W_g   = (const float*)d_in[4];
    const float* W_e   = (const float*)d_in[5];
    const float* O_e   = (const float*)d_in[6];

    float* n_out = (float*)d_out;
    float* e_out = n_out + (size_t)BB * NN * DD;

    float* Qw    = (float*)d_ws;                          // 3 x 0.5MB
    float* Kw    = Qw + (size_t)BB * HH * NN * DKK;
    float* Vw    = Kw + (size_t)BB * HH * NN * DKK;
    float* EGw   = Vw + (size_t)BB * HH * NN * DKK;       // 16.8MB
    float* QKc   = EGw + (size_t)BB * HH * NN * NN;       // 16.8MB
    float* Gfull = QKc + (size_t)BB * HH * NN * NN;       // 32KB
    float* WegT  = Gfull + (size_t)BB * NN * HH;          // 8KB

    qkv_kernel<<<BB * NN + 16, 128, 0, stream>>>(n_ptr, W_qkv, W_g, W_e,
                                                 Qw, Kw, Vw, WegT);
    qk_kernel<<<BB * HH * 16, 256, 0, stream>>>(Qw, Kw, QKc);
    eg_kernel<<<BB * NN, 512, 0, stream>>>(e, WegT, O_e, QKc,
                                           EGw, Gfull, e_out);
    attn_kernel<<<BB * NN, 256, 0, stream>>>(EGw, Gfull, Vw, O_n, n_out);
}